// Round 17
// baseline (630.295 us; speedup 1.0000x reference)
//
#include <hip/hip_runtime.h>
#include <stdint.h>

typedef unsigned short u16;
typedef unsigned int u32;
typedef __attribute__((ext_vector_type(8))) short bf16x8;
typedef __attribute__((ext_vector_type(8))) unsigned short u16x8;
typedef __attribute__((ext_vector_type(2))) unsigned int u32x2;
typedef __attribute__((ext_vector_type(4))) float f32x4;

#define LB256 __launch_bounds__(256, 2)
#define LBG __launch_bounds__(256, 4)   // GEMM: cap 128 regs/wave -> 4 blocks/CU

// ---- problem dims ----
#define BB 4
#define NX 1024
#define NC 154
#define NT 1178
#define NTP 1184   // padded t stride for V^T (16B-aligned rows)
#define DD 1536
#define HH 24
#define MHD 6144
#define NQKV 4608
#define NMOD 9216
#define KSPL 6

__device__ __forceinline__ int imin(int a, int b) { return a < b ? a : b; }

__device__ __forceinline__ u16 f2bf(float f) {
  u32 u = __float_as_uint(f);
  u32 r = (u + 0x7fffu + ((u >> 16) & 1u)) >> 16;
  return (u16)r;
}

__device__ __forceinline__ float bf2f(u16 v) {
  u32 u = ((u32)v) << 16;
  return __uint_as_float(u);
}

// tanh-gelu via sigmoid identity: 0.5x(1+tanh(z)) == x * sigmoid(2z)
__device__ __forceinline__ float gelu_t(float x) {
  float u = 1.5957691216f * x * fmaf(0.044715f, x * x, 1.f);
  return x / (1.f + __expf(-u));
}

__device__ __forceinline__ f32x4 fzero4() {
  f32x4 z; z[0] = 0.f; z[1] = 0.f; z[2] = 0.f; z[3] = 0.f; return z;
}

// async global->LDS, 16B per lane; LDS dest = wave-uniform base + lane*16
__device__ __forceinline__ void glds16(const u16* g, u16* l) {
  __builtin_amdgcn_global_load_lds(
      (const __attribute__((address_space(1))) void*)g,
      (__attribute__((address_space(3))) void*)l, 16, 0, 0);
}

#define WAITV0 asm volatile("s_waitcnt vmcnt(0)" ::: "memory")
#define SCHEDB __builtin_amdgcn_sched_barrier(0)

// ---- batched weight transpose + f32->bf16 (8 matrices) AND silu-mod partials,
// one dispatch. Blocks >= off[8] run the mod-partial role.
struct TDesc {
  const float* W[8];
  u16* Wt[8];
  int K[8];
  int N[8];
  int off[9];  // prefix block offsets
  const float* vec;
  const float* w_mod;
  float* part;
};

__global__ void k_transpose8(TDesc d) {
  __shared__ float shf[32 * 33];
  int bid = blockIdx.x;
  if (bid >= d.off[8]) {
    // ---- mod partial role: part[kb][b][n] = sum_k silu(vec)[b][k0+k] * w_mod[k0+k][n]
    float(*sv)[256] = (float(*)[256])shf;
    const int local = bid - d.off[8];
    const int kb = local / (NMOD / 256);
    const int n = (local % (NMOD / 256)) * 256 + threadIdx.x;
    const int k0 = kb * 256;
    for (int i = threadIdx.x; i < BB * 256; i += 256) {
      int b = i >> 8, kk = i & 255;
      float v = d.vec[b * DD + k0 + kk];
      sv[b][kk] = v / (1.f + __expf(-v));
    }
    __syncthreads();
    float a0 = 0.f, a1 = 0.f, a2 = 0.f, a3 = 0.f;
    for (int k = 0; k < 256; ++k) {
      float w = d.w_mod[(size_t)(k0 + k) * NMOD + n];
      a0 = fmaf(sv[0][k], w, a0);
      a1 = fmaf(sv[1][k], w, a1);
      a2 = fmaf(sv[2][k], w, a2);
      a3 = fmaf(sv[3][k], w, a3);
    }
    d.part[((size_t)kb * BB + 0) * NMOD + n] = a0;
    d.part[((size_t)kb * BB + 1) * NMOD + n] = a1;
    d.part[((size_t)kb * BB + 2) * NMOD + n] = a2;
    d.part[((size_t)kb * BB + 3) * NMOD + n] = a3;
    return;
  }
  // ---- transpose role (float2 loads, packed-u32 bf16 stores)
  int i = 0;
#pragma unroll
  for (int t = 1; t < 8; ++t)
    if (bid >= d.off[t]) i = t;
  const float* W = d.W[i];
  u16* Wt = d.Wt[i];
  const int K = d.K[i], N = d.N[i];
  const int local = bid - d.off[i];
  const int nbx = N >> 5;
  const int n0 = (local % nbx) * 32, k0 = (local / nbx) * 32;
  const int cx = threadIdx.x & 15, ry = threadIdx.x >> 4;  // 16 x 16
#pragma unroll
  for (int j = 0; j < 32; j += 16) {
    float2 t2 = *(const float2*)&W[(size_t)(k0 + ry + j) * N + n0 + cx * 2];
    shf[(ry + j) * 33 + cx * 2] = t2.x;
    shf[(ry + j) * 33 + cx * 2 + 1] = t2.y;
  }
  __syncthreads();
#pragma unroll
  for (int j = 0; j < 32; j += 16) {
    const int ny = ry + j;
    u32 w = (u32)f2bf(shf[(cx * 2) * 33 + ny]) | ((u32)f2bf(shf[(cx * 2 + 1) * 33 + ny]) << 16);
    *(u32*)&Wt[(size_t)(n0 + ny) * K + k0 + cx * 2] = w;
  }
}

__global__ void k_mod_red(const float* __restrict__ part, const float* __restrict__ b_mod,
                          float* __restrict__ mod) {
  int n = blockIdx.x * 256 + threadIdx.x;
  float bb = b_mod[n];
#pragma unroll
  for (int b = 0; b < BB; ++b) {
    float s = bb;
#pragma unroll
    for (int kb = 0; kb < KSPL; ++kb) s += part[((size_t)kb * BB + b) * NMOD + n];
    mod[b * NMOD + n] = s;
  }
}

// ---- merged dual-stream LayerNorm f32 -> bf16, float2-vectorized ----
// rows [0, BB*NX) = stream 1; rest = stream 2. modp==nullptr -> plain LN.
__global__ LB256 void k_ln2(const float* __restrict__ in1, u16* __restrict__ out1,
                            const float* __restrict__ in2, u16* __restrict__ out2,
                            const float* __restrict__ modp, int sh1, int sc1,
                            int sh2, int sc2) {
  int row = blockIdx.x;
  const float* xr;
  u16* outp;
  int b, sh, sc;
  if (row < BB * NX) {
    xr = in1 + (size_t)row * DD;
    outp = out1 + (size_t)row * DD;
    b = row / NX; sh = sh1; sc = sc1;
  } else {
    int r2 = row - BB * NX;
    xr = in2 + (size_t)r2 * DD;
    outp = out2 + (size_t)r2 * DD;
    b = r2 / NC; sh = sh2; sc = sc2;
  }
  const float2* x2p = (const float2*)xr;
  float2 v[3];
  float s = 0.f, s2 = 0.f;
#pragma unroll
  for (int i = 0; i < 3; ++i) {
    float2 t = x2p[threadIdx.x + 256 * i];
    v[i] = t;
    s += t.x + t.y;
    s2 += t.x * t.x + t.y * t.y;
  }
#pragma unroll
  for (int m = 32; m >= 1; m >>= 1) {
    s += __shfl_xor(s, m);
    s2 += __shfl_xor(s2, m);
  }
  __shared__ float red[8];
  int wid = threadIdx.x >> 6;
  if ((threadIdx.x & 63) == 0) { red[wid] = s; red[4 + wid] = s2; }
  __syncthreads();
  s = red[0] + red[1] + red[2] + red[3];
  s2 = red[4] + red[5] + red[6] + red[7];
  float mean = s * (1.f / (float)DD);
  float var = s2 * (1.f / (float)DD) - mean * mean;
  float rstd = rsqrtf(var + 1e-6f);
#pragma unroll
  for (int i = 0; i < 3; ++i) {
    int d = (threadIdx.x + 256 * i) * 2;
    float y0 = (v[i].x - mean) * rstd;
    float y1 = (v[i].y - mean) * rstd;
    if (modp) {
      float2 scv = *(const float2*)&modp[b * NMOD + sc + d];
      float2 shv = *(const float2*)&modp[b * NMOD + sh + d];
      y0 = y0 * (1.f + scv.x) + shv.x;
      y1 = y1 * (1.f + scv.y) + shv.y;
    }
    u32 w = (u32)f2bf(y0) | ((u32)f2bf(y1) << 16);
    *(u32*)&outp[d] = w;
  }
}

// ---- GEMM epilogue variants ----
// 0 bias->bf16 | 1 gelu->bf16 | 2 resid+g*(acc+bias)->f32 | 3 resid+acc+bias->f32
// 4 acc->bf16 partial at outp + zed*goff | 5 qkv scatter (q,k (b,h,t,d); v^T,
//   packed u32 t-pair stores where the 4 in-lane rows share a batch)
template <int EPI>
__device__ __forceinline__ void gemm_epi(
    const f32x4 (&acc)[4][4], int m0, int n0, int wm, int wn, int g, int r,
    int M, int N, const float* bias, void* outp, const float* resid,
    const float* modp, int goff, int rpb, int zed,
    u16* qb, u16* kb, u16* vtb) {
#pragma unroll
  for (int mi = 0; mi < 4; ++mi) {
#pragma unroll
    for (int ni = 0; ni < 4; ++ni) {
      const int col = n0 + wn + ni * 16 + r;
      float bv = 0.f;
      if constexpr (EPI != 4) bv = bias[col];
      if constexpr (EPI == 5) {
        const int row0 = m0 + wm + mi * 16 + g * 4;
        if (col >= 2 * DD) {
          // V^T: 4 in-lane rows = 4 consecutive t. Packed when same batch & in-range.
          const int cc = col - 2 * DD;
          const int h = cc >> 6, d = cc & 63;
          const int b0 = row0 / rpb;
          if (row0 + 3 < M && (row0 + 3) / rpb == b0) {
            const int t = goff + (row0 - b0 * rpb);
            u16* dst = &vtb[((size_t)b0 * HH + h) * (64 * NTP) + (size_t)d * NTP + t];
            u32 w0 = (u32)f2bf(acc[mi][ni][0] + bv) | ((u32)f2bf(acc[mi][ni][1] + bv) << 16);
            u32 w1 = (u32)f2bf(acc[mi][ni][2] + bv) | ((u32)f2bf(acc[mi][ni][3] + bv) << 16);
            *(u32*)&dst[0] = w0;
            *(u32*)&dst[2] = w1;
          } else {
#pragma unroll
            for (int j = 0; j < 4; ++j) {
              const int row = row0 + j;
              if (row >= M) continue;
              const int b = row / rpb;
              const int t = goff + (row - b * rpb);
              vtb[((size_t)b * HH + h) * (64 * NTP) + (size_t)d * NTP + t] =
                  f2bf(acc[mi][ni][j] + bv);
            }
          }
        } else {
          const bool isQ = col < DD;
          const int cc = isQ ? col : col - DD;
          const int h = cc >> 6, d = cc & 63;
          u16* dstb = isQ ? qb : kb;
#pragma unroll
          for (int j = 0; j < 4; ++j) {
            const int row = row0 + j;
            if (row >= M) continue;
            const int b = row / rpb;
            const int t = goff + (row - b * rpb);
            dstb[(((size_t)b * HH + h) * NT + t) * 64 + d] = f2bf(acc[mi][ni][j] + bv);
          }
        }
      } else {
#pragma unroll
        for (int j = 0; j < 4; ++j) {
          const int row = m0 + wm + mi * 16 + g * 4 + j;
          if (row >= M) continue;
          const size_t off = (size_t)row * N + col;
          float v = acc[mi][ni][j] + bv;
          if constexpr (EPI == 0) {
            ((u16*)outp)[off] = f2bf(v);
          } else if constexpr (EPI == 1) {
            ((u16*)outp)[off] = f2bf(gelu_t(v));
          } else if constexpr (EPI == 2) {
            const int b = row / rpb;
            ((float*)outp)[off] = resid[off] + modp[b * NMOD + goff + col] * v;
          } else if constexpr (EPI == 3) {
            ((float*)outp)[off] = resid[off] + v;
          } else {
            ((u16*)outp)[(size_t)zed * (size_t)goff + off] = f2bf(acc[mi][ni][j]);
          }
        }
      }
    }
  }
}

// ---- merged dual-stream pipelined bf16 MFMA GEMM, 128x128x32 tile ----
// Role 1 (m-blocks [0,yHi)) uses arg-set 1 / EPI1; role 2 uses set 2 / EPI2.
// blockIdx.z split-K (kzOff element offset) applies to BOTH roles.
// Panel-major rasterization (8-wide n-panels, m-fast) keeps each XCD chunk's
// B working-set ~3 MB (L2-resident). 2 x 16KB LDS double-buffer (32 KB total).
// LBG(256,4): 128-reg budget (acc 64 AGPR + ~60 VGPR fits) -> 4 blocks/CU.
// Requires kLen % 32 == 0.
template <int EPI1, int EPI2>
__global__ LBG void k_gemm2(
    const u16* __restrict__ A1, const u16* __restrict__ Bt1, const float* __restrict__ bias1,
    int M1, int rpb1, int goff1, int kLen1,
    const u16* __restrict__ A2, const u16* __restrict__ Bt2, const float* __restrict__ bias2,
    int M2, int rpb2, int goff2, int kLen2,
    int yHi, int N, int lda, int ldb, int kzOff,
    void* __restrict__ out1, void* __restrict__ out2,
    const float* __restrict__ resid1, const float* __restrict__ resid2,
    const float* __restrict__ modp,
    u16* __restrict__ qb, u16* __restrict__ kb, u16* __restrict__ vtb) {
  __shared__ __align__(16) u16 sm[2 * 8192];  // 2 bufs x (A 4K u16 | B 4K u16) = 32 KB
  const int tid = threadIdx.x;
  const int lane = tid & 63;
  const int g = lane >> 4, r = lane & 15;
  const int wid = tid >> 6;

  // bijective XCD-aware tile remap (m204) over the full (gx x gyTot) grid
  const int gx = gridDim.x;
  const int gyTot = gridDim.y;
  const int nwg = gx * gyTot;
  int wg = blockIdx.y * gx + blockIdx.x;
  {
    int q = nwg >> 3, rr = nwg & 7;
    int xcd = wg & 7, sl = wg >> 3;
    wg = (xcd < rr ? xcd * (q + 1) : rr * (q + 1) + (xcd - rr) * q) + sl;
  }
  // panel-major (8-wide n-panels, m-fast within panel), bijective for any gx
  int mIdx, nIdx;
  {
    const int np1 = (gx - 1) >> 3;       // number of full 8-wide panels
    const int lastw = gx - np1 * 8;      // width of last panel (1..8)
    const int full = gyTot * 8;
    if (wg < np1 * full) {
      int p = wg / full, off = wg % full;
      mIdx = off >> 3;
      nIdx = p * 8 + (off & 7);
    } else {
      int off = wg - np1 * full;
      mIdx = off / lastw;
      nIdx = np1 * 8 + off % lastw;
    }
  }
  const bool role2 = mIdx >= yHi;

  const u16* A = role2 ? A2 : A1;
  const u16* Bt = role2 ? Bt2 : Bt1;
  const int M = role2 ? M2 : M1;
  const int kLen = role2 ? kLen2 : kLen1;
  const int m0 = (role2 ? (mIdx - yHi) : mIdx) * 128, n0 = nIdx * 128;
  const int wm = (wid >> 1) * 64, wn = (wid & 1) * 64;
  A += (size_t)blockIdx.z * kzOff;
  Bt += (size_t)blockIdx.z * kzOff;

  f32x4 acc[4][4];
#pragma unroll
  for (int i = 0; i < 4; ++i)
#pragma unroll
    for (int j = 0; j < 4; ++j) acc[i][j] = fzero4();

  // staging geometry (proven, 0 bank conflicts): wave wid owns chunks c0,c1;
  // lane l -> row c*16 + l/4, phys slot l&3 holds logical slot (l&3)^((l>>3)&3)
  const int rl = lane >> 2;
  const int slg = (lane & 3) ^ ((lane >> 3) & 3);
  const int c0 = wid * 2, c1 = wid * 2 + 1;
  const size_t aR0 = (size_t)imin(m0 + c0 * 16 + rl, M - 1) * lda + slg * 8;
  const size_t aR1 = (size_t)imin(m0 + c1 * 16 + rl, M - 1) * lda + slg * 8;
  const size_t bR0 = (size_t)(n0 + c0 * 16 + rl) * ldb + slg * 8;
  const size_t bR1 = (size_t)(n0 + c1 * 16 + rl) * ldb + slg * 8;

  int aOff[4], bOff[4];
#pragma unroll
  for (int mi = 0; mi < 4; ++mi) aOff[mi] = (wm + mi * 16 + r) * 32 + ((g ^ ((r >> 1) & 3)) * 8);
#pragma unroll
  for (int ni = 0; ni < 4; ++ni) bOff[ni] = 4096 + (wn + ni * 16 + r) * 32 + ((g ^ ((r >> 1) & 3)) * 8);

  const int nt = kLen >> 5;  // K-steps of 32

#define STAGE32(BI, T)                                      \
  do {                                                      \
    u16* bb = &sm[(BI) * 8192];                             \
    size_t kk = (size_t)(T) * 32;                           \
    glds16(A + aR0 + kk, bb + c0 * 512);                    \
    glds16(A + aR1 + kk, bb + c1 * 512);                    \
    glds16(Bt + bR0 + kk, bb + 4096 + c0 * 512);            \
    glds16(Bt + bR1 + kk, bb + 4096 + c1 * 512);            \
  } while (0)

  STAGE32(0, 0);

  for (int t = 0; t < nt; ++t) {
    WAITV0;                              // my 4 tile-t loads landed
    __builtin_amdgcn_s_barrier();        // tile-t published; tile-(t-1) reads retired
    SCHEDB;
    if (t + 1 < nt) STAGE32((t + 1) & 1, t + 1);  // lands during this tile's compute
    const u16* bb = &sm[(t & 1) * 8192];
    bf16x8 af[4], bfr[4];
#pragma unroll
    for (int mi = 0; mi < 4; ++mi) af[mi] = *(const bf16x8*)(bb + aOff[mi]);
#pragma unroll
    for (int ni = 0; ni < 4; ++ni) bfr[ni] = *(const bf16x8*)(bb + bOff[ni]);
    __builtin_amdgcn_s_setprio(1);
#pragma unroll
    for (int mi = 0; mi < 4; ++mi)
#pragma unroll
      for (int ni = 0; ni < 4; ++ni)
        acc[mi][ni] = __builtin_amdgcn_mfma_f32_16x16x32_bf16(af[mi], bfr[ni], acc[mi][ni], 0, 0, 0);
    __builtin_amdgcn_s_setprio(0);
    SCHEDB;  // keep this tile's body ahead of next iteration's WAITV0
  }
#undef STAGE32

  if (role2)
    gemm_epi<EPI2>(acc, m0, n0, wm, wn, g, r, M, N, bias2, out2, resid2, modp,
                   goff2, rpb2, blockIdx.z, qb, kb, vtb);
  else
    gemm_epi<EPI1>(acc, m0, n0, wm, wn, g, r, M, N, bias1, out1, resid1, modp,
                   goff1, rpb1, blockIdx.z, qb, kb, vtb);
}

// ---- split-K reduce for mlp2 (x rows then c rows), float2/u32-vectorized ----
__global__ void k_red2(const u16* __restrict__ p0x, const u16* __restrict__ p1x,
                       const float* __restrict__ residx, const float* __restrict__ bx,
                       const u16* __restrict__ p0c, const u16* __restrict__ p1c,
                       const float* __restrict__ residc, const float* __restrict__ bc,
                       float* __restrict__ outx, float* __restrict__ outc) {
  int row = blockIdx.x;
  const u16 *p0, *p1;
  const float *resid, *bias;
  float* out;
  size_t base;
  if (row < BB * NX) {
    p0 = p0x; p1 = p1x; resid = residx; bias = bx; out = outx;
    base = (size_t)row * DD;
  } else {
    int r2 = row - BB * NX;
    p0 = p0c; p1 = p1c; resid = residc; bias = bc; out = outc;
    base = (size_t)r2 * DD;
  }
#pragma unroll
  for (int i = 0; i < 3; ++i) {
    int j2 = (threadIdx.x + 256 * i) * 2;
    u32 a = *(const u32*)&p0[base + j2];
    u32 b = *(const u32*)&p1[base + j2];
    float2 rv = *(const float2*)&resid[base + j2];
    float2 bv = *(const float2*)&bias[j2];
    float2 o;
    o.x = rv.x + bv.x + bf2f((u16)a) + bf2f((u16)b);
    o.y = rv.y + bv.y + bf2f((u16)(a >> 16)) + bf2f((u16)(b >> 16));
    *(float2*)&out[base + j2] = o;
  }
}

// ---- flash attention: QBLK=128 (8 waves x 16 rows), KBLK=64, HD=64 ----
// Swapped QK^T (S^T = mfma(K,Q)): lane owns q-row (lane&15), 16 in-lane t.
// In-register softmax, packed b64 P-writes, next-tile K/V register prefetch
// (edge-specialized: clean path for 18/19 tiles), defer-max (THR=0, exact).
__global__ __launch_bounds__(512, 2) void k_attn(
    const u16* __restrict__ q, const u16* __restrict__ kk,
    const u16* __restrict__ vt, u16* __restrict__ ox, u16* __restrict__ oc) {
  __shared__ __align__(16) u16 Ks[64][72];
  __shared__ __align__(16) u16 Vs[64][72];
  __shared__ __align__(16) u16 Ps[8][16][72];

  const int lane = threadIdx.x & 63, wid = threadIdx.x >> 6;  // wid 0..7
  const int g = lane >> 4, r = lane & 15;
  const int q0 = blockIdx.x * 128;
  const int h = blockIdx.y, b = blockIdx.z;
  const size_t bh = (size_t)b * HH + h;
  const u16* qp = q + bh * (NT * 64);
  const u16* kp = kk + bh * (NT * 64);
  const u16* vp = vt + bh * (64 * NTP);

  const int qrow = imin(q0 + wid * 16 + r, NT - 1);
  u16x8 qr0 = *(const u16x8*)(qp + (size_t)qrow * 64 + g * 8);
  u16x8 qr1 = *(const u16x8*)(qp + (size_t)qrow * 64 + 32 + g * 8);
  bf16x8 qa0, qa1;
#pragma unroll
  for (int e = 0; e < 8; ++e) {
    qa0[e] = (short)f2bf(bf2f(qr0[e]) * 0.125f);
    qa1[e] = (short)f2bf(bf2f(qr1[e]) * 0.125f);
  }

  f32x4 oacc[4];
#pragma unroll
  for (int i = 0; i < 4; ++i) oacc[i] = fzero4();
  float mrow = -1e30f, lrow = 0.f;

  const int trA = threadIdx.x >> 3;
  const int ccA = (threadIdx.x & 7) * 8;

  u16x8 kreg, vreg;
#define LOADKV_C(T0)                                                   \
  do {                                                                 \
    kreg = *(const u16x8*)(kp + (size_t)((T0) + trA) * 64 + ccA);      \
    vreg = *(const u16x8*)(vp + (size_t)trA * NTP + (T0) + ccA);       \
  } while (0)
#define LOADKV_E(T0)                                                   \
  do {                                                                 \
    int tsrc = imin((T0) + trA, NT - 1);                               \
    kreg = *(const u16x8*)(kp + (size_t)tsrc * 64 + ccA);              \
    int tcol = (T0) + ccA;                                             \
    if (tcol + 8 <= NT) {                                              \
      vreg = *(const u16x8*)(vp + (size_t)trA * NTP + tcol);           \
    } else {                                                           \
      _Pragma("unroll")                                                \
      for (int e = 0; e < 8; ++e)                                      \
        vreg[e] = vp[(size_t)trA * NTP + imin(tcol + e, NT - 1)];      \
    }                                                                  \
  } while (0)

  LOADKV_C(0);

  for (int t0 = 0; t0 < NT; t0 += 64) {
    if (t0) __syncthreads();
    *(u16x8*)&Ks[trA][ccA] = kreg;
    *(u16x8*)&Vs[trA][ccA] = vreg;
    __syncthreads();
    if (t0 + 64 < NT) {
      if (t0 + 128 > NT) LOADKV_E(t0 + 64);  // next tile is the ragged last one
      else LOADKV_C(t0 + 64);
    }

    f32x4 s[4];
#pragma unroll
    for (int ni = 0; ni < 4; ++ni) {
      s[ni] = fzero4();
      s[ni] = __builtin_amdgcn_mfma_f32_16x16x32_bf16(*(const bf16x8*)&Ks[ni * 16 + r][g * 8], qa0, s[ni], 0, 0, 0);
      s[ni] = __builtin_amdgcn_mfma_f32_16x16x32_bf16(*(const bf16x8*)&Ks[ni * 16 + r][32 + g * 8], qa1, s[ni], 0, 0, 0);
    }

    float pv[4][4];
    float pm = -1e30f;
#pragma unroll
    for (int ni = 0; ni < 4; ++ni)
#pragma unroll
      for (int j = 0; j < 4; ++j) {
        int t = t0 + ni * 16 + g * 4 + j;
        float sv = (t < NT) ? s[ni][j] : -1e30f;
        pv[ni][j] = sv;
        pm = fmaxf(pm, sv);
      }
    pm = fmaxf(pm, __shfl_xor(pm, 16));
    pm = fmaxf(pm, __shfl_xor(pm, 32));

    // defer-max with THR=0: when no q-row's max grew, alpha == 1 exactly.
    const bool grow = !__all(pm <= mrow);
    float mn = mrow;
    if (grow) mn = fmaxf(mrow, pm);
    float rs = 0.f;
#pragma unroll
    for (int ni = 0; ni < 4; ++ni)
#pragma unroll
      for (int j = 0; j < 4; ++j) {
        float p = __expf(pv[ni][j] - mn);
        pv[ni][j] = p;
        rs += p;
      }
    rs += __shfl_xor(rs, 16);
    rs += __shfl_xor(rs, 32);
    if (grow) {
      float alpha = __expf(mrow - mn);
      mrow = mn;
      lrow = lrow * alpha + rs;
#pragma unroll
      for (int j = 0; j < 4; ++j) {
        float aj = __shfl(alpha, g * 4 + j);
#pragma unroll
        for (int ni = 0; ni < 4; ++ni) oacc[ni][j] *= aj;
      }
    } else {
      lrow += rs;
    }

#pragma unroll
    for (int ni = 0; ni < 4; ++ni) {
      u32x2 w;
      w[0] = (u32)f2bf(pv[ni][0]) | ((u32)f2bf(pv[ni][1]) << 16);
      w[1] = (u32)f2bf(pv[ni][2]) | ((u32)f2bf(pv[ni][3]) << 16);
      *(u32x2*)&Ps[wid][r][ni * 16 + g * 4] = w;
    }

    bf16x8 pa0 = *(const bf16x8*)&Ps[wid][r][g * 8];
    bf16x8 pa1 = *(const bf16x8*)&Ps[wid][r][32 + g * 8];
#pragma unroll
    for (int ni = 0; ni < 4; ++ni) {
      oacc[ni] = __builtin_amdgcn_mfma_f32_16x16x32_bf16(pa0, *(const bf16x8*)&Vs[ni * 16 + r][g * 8], oacc[ni], 0, 0, 0);
      oacc[ni] = __builtin_amdgcn_mfma_f32_16x16x32_bf16(pa1, *(const bf16x8*)&Vs[ni * 16 + r][32 + g * 8], oacc[ni], 0, 0, 0);
    }
  }
#undef LOADKV_C
#undef LOADKV_E

  float linv[4];
#pragma unroll
  for (int j = 0; j < 4; ++j) linv[j] = 1.f / __shfl(lrow, g * 4 + j);

#pragma unroll
  for (int ni = 0; ni < 4; ++ni)
#pragma unroll
    for (int j = 0; j < 4; ++j) {
      int tq = q0 + wid * 16 + g * 4 + j;
      if (tq >= NT) continue;
      float val = oacc[ni][j] * linv[j];
      int col = h * 64 + ni * 16 + r;
      if (tq < NX)
        ox[(size_t)(b * NX + tq) * DD + col] = f2bf(val);
      else
        oc[(size_t)(b * NC + tq - NX) * DD + col] = f2bf(val);
    }
}

extern "C" void kernel_launch(void* const* d_in, const int* in_sizes, int n_in,
                              void* d_out, int out_size, void* d_ws, size_t ws_size,
                              hipStream_t stream) {
  const float* x = (const float*)d_in[0];
  const float* c = (const float*)d_in[1];
  const float* vec = (const float*)d_in[2];
  const float* w_mod = (const float*)d_in[3];
  const float* b_mod = (const float*)d_in[4];
  const float* w_qkv_x = (const float*)d_in[5];
  const float* b_qkv_x = (const float*)d_in[6];
  const float* w_qkv_c = (const float*)d_in[7];
  const float* b_qkv_c = (const float*)d_in[8];
  const float* w_proj_x = (const float*)d_in[9];
  const float* b_proj_x = (const float*)d_in[10];
  const float* w_proj_c = (const float*)d_in[11];
  const float* b_proj_c = (const float*)d_in[12];
  const float* w1_x = (const float*)d_in[13];
  const float* b1_x = (const float*)d_in[14];
  const float* w2_x = (const float*)d_in[15];
  const float* b2_x = (const float*)d_in[16];
  const float* w1_c = (const float*)d_in[17];
  const float* b1_c = (const float*)d_in[18];
  const float* w2_c = (const float*)d_in[19];
  const float* b2_c = (const float*)d_in[20];

  if (ws_size < 229195776ull) return;  // workspace layout below needs this much

  char* ws = (char*)d_ws;
  // persistent: bf16-transposed weights + mod
  u16* wt_qkv_x = (u16*)(ws + 0);
  u16* wt_qkv_c = (u16*)(ws + 14155776);
  u16* wt_proj_x = (u16*)(ws + 28311552);
  u16* wt_proj_c = (u16*)(ws + 33030144);
  u16* wt_w1_x = (u16*)(ws + 37748736);
  u16* wt_w1_c = (u16*)(ws + 56623104);
  u16* wt_w2_x = (u16*)(ws + 75497472);
  u16* wt_w2_c = (u16*)(ws + 94371840);
  float* modf = (float*)(ws + 113246208);
  char* S = ws + 113393664;
  // slot 1 (14,475,264 B): x_n/c_n -> o_x/o_c -> xln/cln -> pb0 + pc0
  u16* xn = (u16*)(S);
  u16* cn = (u16*)(S + 12582912);
  // slot 2 (43,425,792 B): x2/c2 (f32); pb1 follows, then pc1 gap
  float* x2 = (float*)(S + 14475264);   // 25,165,824 B, ends S+39,641,088
  float* c2 = (float*)(S + 39641088);   //  3,784,704 B, ends S+43,425,792
  u16* pb0 = (u16*)(S);                 // 12,582,912 B (xn dead after mlp1 reads)
  u16* pc0 = (u16*)(S + 12582912);      //  1,892,352 B (cn dead after mlp1 reads)
  u16* pb1 = (u16*)(S + 43425792);      // 12,582,912 B (dead region after c2)
  u16* pc1 = (u16*)(S + 56008704);      //  1,892,352 B (gap before slot 3)
  const int PSTRIDE = 43425792 / 2;     // u16 stride pb0->pb1 AND pc0->pc1
  // slot 3 (57,901,056 B): q/k/vt -> h_x/h_c ; head also used as k_mod partials
  u16* qb = (u16*)(S + 57901056);
  u16* kb = (u16*)(S + 72376320);
  u16* vtb = (u16*)(S + 86851584);
  u16* hx = (u16*)(S + 57901056);
  u16* hc = (u16*)(S + 108232704);
  float* modpart = (float*)(S + 57901056);  // dead before q/k/vt written

  // 1) all 8 weight transposes + mod partials in ONE dispatch
  {
    TDesc d;
    const float* Ws[8] = {w_qkv_x, w_qkv_c, w_proj_x, w_proj_c, w1_x, w1_c, w2_x, w2_c};
    u16* Wts[8] = {wt_qkv_x, wt_qkv_c, wt_proj_x, wt_proj_c, wt_w1_x, wt_w1_c, wt_w2_x, wt_w2_c};
    int Ks[8] = {DD, DD, DD, DD, DD, DD, MHD, MHD};
    int Ns[8] = {NQKV, NQKV, DD, DD, MHD, MHD, DD, DD};
    int off = 0;
    for (int i = 0; i < 8; ++i) {
      d.W[i] = Ws[i]; d.Wt[i] = Wts[i]; d.K[i] = Ks[i]; d.N[i] = Ns[i];
      d.off[i] = off;
      off += (Ns[i] >> 5) * (Ks[i] >> 5);
    }
    d.off[8] = off;
    d.vec = vec;
    d.w_mod = w_mod;
    d.part = modpart;
    k_transpose8<<<dim3(off + (NMOD / 256) * KSPL), 256, 0, stream>>>(d);
  }

  // 2) mod reduce (deterministic)
  k_mod_red<<<dim3(NMOD / 256), 256, 0, stream>>>(modpart, b_mod, modf);

  // 3) modulated LN (x+c merged) -> bf16
  k_ln2<<<dim3(BB * (NX + NC)), 256, 0, stream>>>(x, xn, c, cn, modf, 0, DD, 3 * DD, 4 * DD);

  // 4) merged QKV GEMM (x+c) with scatter epilogue -> qb,kb,vtb directly
  k_gemm2<5, 5><<<dim3(NQKV / 128, 37), 256, 0, stream>>>(
      xn, wt_qkv_x, b_qkv_x, BB * NX, NX, 0, DD,
      cn, wt_qkv_c, b_qkv_c, BB * NC, NC, NX, DD,
      32, NQKV, DD, DD, 0, nullptr, nullptr, nullptr, nullptr, nullptr,
      qb, kb, vtb);

  // 5) flash attention (QBLK=128, 8 waves) -> o (written into slot 1)
  k_attn<<<dim3((NT + 127) / 128, HH, BB), 512, 0, stream>>>(qb, kb, vtb, xn, cn);

  // 6) merged output projections with gated residual -> x2/c2 f32
  k_gemm2<2, 2><<<dim3(DD / 128, 37), 256, 0, stream>>>(
      xn, wt_proj_x, b_proj_x, BB * NX, NX, 2 * DD, DD,
      cn, wt_proj_c, b_proj_c, BB * NC, NC, 5 * DD, DD,
      32, DD, DD, DD, 0, x2, c2, x, c, modf, nullptr, nullptr, nullptr);

  // 7) plain LN (x+c merged) -> bf16
  k_ln2<<<dim3(BB * (NX + NC)), 256, 0, stream>>>(x2, xn, c2, cn, nullptr, 0, 0, 0, 0);

  // 8) merged MLP-1 (gelu) -> hx/hc
  k_gemm2<1, 1><<<dim3(MHD / 128, 37), 256, 0, stream>>>(
      xn, wt_w1_x, b1_x, BB * NX, NX, 0, DD,
      cn, wt_w1_c, b1_c, BB * NC, NC, 0, DD,
      32, MHD, DD, DD, 0, hx, hc, nullptr, nullptr, nullptr, nullptr, nullptr, nullptr);

  float* outx = (float*)d_out;
  float* outc = outx + (size_t)BB * NX * DD;
  // 9) merged MLP-2: BOTH streams split-K over z (96 K-steps every block)
  k_gemm2<4, 4><<<dim3(DD / 128, 37, 2), 256, 0, stream>>>(
      hx, wt_w2_x, b2_x, BB * NX, NX, PSTRIDE, MHD / 2,
      hc, wt_w2_c, b2_c, BB * NC, NC, PSTRIDE, MHD / 2,
      32, DD, MHD, MHD, MHD / 2, pb0, pc0, nullptr, nullptr, nullptr,
      nullptr, nullptr, nullptr);
  k_red2<<<dim3(BB * (NX + NC)), 256, 0, stream>>>(
      pb0, pb1, x2, b2_x, pc0, pc1, c2, b2_c, outx, outc);
}

// Round 18
// 628.931 us; speedup vs baseline: 1.0022x; 1.0022x over previous
//
#include <hip/hip_runtime.h>
#include <stdint.h>

typedef unsigned short u16;
typedef unsigned int u32;
typedef __attribute__((ext_vector_type(8))) short bf16x8;
typedef __attribute__((ext_vector_type(8))) unsigned short u16x8;
typedef __attribute__((ext_vector_type(2))) unsigned int u32x2;
typedef __attribute__((ext_vector_type(4))) float f32x4;

#define LB256 __launch_bounds__(256, 2)
#define LBG __launch_bounds__(256, 4)   // GEMM: cap 128 regs/wave -> 4 blocks/CU

// ---- problem dims ----
#define BB 4
#define NX 1024
#define NC 154
#define NT 1178
#define NTP 1184   // padded t stride for V^T (16B-aligned rows)
#define DD 1536
#define HH 24
#define MHD 6144
#define NQKV 4608
#define NMOD 9216
#define KSPL 6

__device__ __forceinline__ int imin(int a, int b) { return a < b ? a : b; }

__device__ __forceinline__ u16 f2bf(float f) {
  u32 u = __float_as_uint(f);
  u32 r = (u + 0x7fffu + ((u >> 16) & 1u)) >> 16;
  return (u16)r;
}

__device__ __forceinline__ float bf2f(u16 v) {
  u32 u = ((u32)v) << 16;
  return __uint_as_float(u);
}

// tanh-gelu via sigmoid identity: 0.5x(1+tanh(z)) == x * sigmoid(2z)
__device__ __forceinline__ float gelu_t(float x) {
  float u = 1.5957691216f * x * fmaf(0.044715f, x * x, 1.f);
  return x / (1.f + __expf(-u));
}

__device__ __forceinline__ f32x4 fzero4() {
  f32x4 z; z[0] = 0.f; z[1] = 0.f; z[2] = 0.f; z[3] = 0.f; return z;
}

// async global->LDS, 16B per lane; LDS dest = wave-uniform base + lane*16
__device__ __forceinline__ void glds16(const u16* g, u16* l) {
  __builtin_amdgcn_global_load_lds(
      (const __attribute__((address_space(1))) void*)g,
      (__attribute__((address_space(3))) void*)l, 16, 0, 0);
}

#define WAITV0 asm volatile("s_waitcnt vmcnt(0)" ::: "memory")
#define SCHEDB __builtin_amdgcn_sched_barrier(0)

// ---- batched weight transpose + f32->bf16 (8 matrices) AND silu-mod partials,
// one dispatch. Blocks >= off[8] run the mod-partial role.
// Transpose: 64x64 f32 tiles; 256B-contiguous row reads (float4 x 4 lanes/row),
// 2x16B u16x8 stores per thread on the output side. LDS [64][65] -> <=2-way
// bank aliasing (free, m136).
struct TDesc {
  const float* W[8];
  u16* Wt[8];
  int K[8];
  int N[8];
  int off[9];  // prefix block offsets (64x64 tiles)
  const float* vec;
  const float* w_mod;
  float* part;
};

__global__ void k_transpose8(TDesc d) {
  __shared__ float tile[64][65];  // 16.6 KB
  int bid = blockIdx.x;
  if (bid >= d.off[8]) {
    // ---- mod partial role: part[kb][b][n] = sum_k silu(vec)[b][k0+k] * w_mod[k0+k][n]
    float(*sv)[256] = (float(*)[256])&tile[0][0];
    const int local = bid - d.off[8];
    const int kb = local / (NMOD / 256);
    const int n = (local % (NMOD / 256)) * 256 + threadIdx.x;
    const int k0 = kb * 256;
    for (int i = threadIdx.x; i < BB * 256; i += 256) {
      int b = i >> 8, kk = i & 255;
      float v = d.vec[b * DD + k0 + kk];
      sv[b][kk] = v / (1.f + __expf(-v));
    }
    __syncthreads();
    float a0 = 0.f, a1 = 0.f, a2 = 0.f, a3 = 0.f;
    for (int k = 0; k < 256; ++k) {
      float w = d.w_mod[(size_t)(k0 + k) * NMOD + n];
      a0 = fmaf(sv[0][k], w, a0);
      a1 = fmaf(sv[1][k], w, a1);
      a2 = fmaf(sv[2][k], w, a2);
      a3 = fmaf(sv[3][k], w, a3);
    }
    d.part[((size_t)kb * BB + 0) * NMOD + n] = a0;
    d.part[((size_t)kb * BB + 1) * NMOD + n] = a1;
    d.part[((size_t)kb * BB + 2) * NMOD + n] = a2;
    d.part[((size_t)kb * BB + 3) * NMOD + n] = a3;
    return;
  }
  // ---- transpose role: W[K][N] (f32) -> Wt[N][K] (bf16), 64x64 tile
  int i = 0;
#pragma unroll
  for (int t = 1; t < 8; ++t)
    if (bid >= d.off[t]) i = t;
  const float* W = d.W[i];
  u16* Wt = d.Wt[i];
  const int K = d.K[i], N = d.N[i];
  const int local = bid - d.off[i];
  const int nbx = N >> 6;
  const int n0 = (local % nbx) * 64, k0 = (local / nbx) * 64;
  const int rr = threadIdx.x >> 2;        // 0..63 (k-row on load, n-row on store)
  const int cc = (threadIdx.x & 3) * 16;  // 0,16,32,48
  // load: row k0+rr, cols n0+cc..cc+15 (4x float4, 64B/thread, 256B/row)
#pragma unroll
  for (int j = 0; j < 4; ++j) {
    float4 t4 = *(const float4*)&W[(size_t)(k0 + rr) * N + n0 + cc + j * 4];
    tile[rr][cc + j * 4 + 0] = t4.x;
    tile[rr][cc + j * 4 + 1] = t4.y;
    tile[rr][cc + j * 4 + 2] = t4.z;
    tile[rr][cc + j * 4 + 3] = t4.w;
  }
  __syncthreads();
  // store: Wt row n0+rr, cols k0+cc..cc+15 as bf16 (2x u16x8 = 32B/thread)
  u16x8 o0, o1;
#pragma unroll
  for (int j = 0; j < 8; ++j) o0[j] = f2bf(tile[cc + j][rr]);
#pragma unroll
  for (int j = 0; j < 8; ++j) o1[j] = f2bf(tile[cc + 8 + j][rr]);
  u16* dst = &Wt[(size_t)(n0 + rr) * K + k0 + cc];
  *(u16x8*)&dst[0] = o0;
  *(u16x8*)&dst[8] = o1;
}

__global__ void k_mod_red(const float* __restrict__ part, const float* __restrict__ b_mod,
                          float* __restrict__ mod) {
  int n = blockIdx.x * 256 + threadIdx.x;
  float bb = b_mod[n];
#pragma unroll
  for (int b = 0; b < BB; ++b) {
    float s = bb;
#pragma unroll
    for (int kb = 0; kb < KSPL; ++kb) s += part[((size_t)kb * BB + b) * NMOD + n];
    mod[b * NMOD + n] = s;
  }
}

// ---- merged dual-stream LayerNorm f32 -> bf16, float2-vectorized ----
// rows [0, BB*NX) = stream 1; rest = stream 2. modp==nullptr -> plain LN.
__global__ LB256 void k_ln2(const float* __restrict__ in1, u16* __restrict__ out1,
                            const float* __restrict__ in2, u16* __restrict__ out2,
                            const float* __restrict__ modp, int sh1, int sc1,
                            int sh2, int sc2) {
  int row = blockIdx.x;
  const float* xr;
  u16* outp;
  int b, sh, sc;
  if (row < BB * NX) {
    xr = in1 + (size_t)row * DD;
    outp = out1 + (size_t)row * DD;
    b = row / NX; sh = sh1; sc = sc1;
  } else {
    int r2 = row - BB * NX;
    xr = in2 + (size_t)r2 * DD;
    outp = out2 + (size_t)r2 * DD;
    b = r2 / NC; sh = sh2; sc = sc2;
  }
  const float2* x2p = (const float2*)xr;
  float2 v[3];
  float s = 0.f, s2 = 0.f;
#pragma unroll
  for (int i = 0; i < 3; ++i) {
    float2 t = x2p[threadIdx.x + 256 * i];
    v[i] = t;
    s += t.x + t.y;
    s2 += t.x * t.x + t.y * t.y;
  }
#pragma unroll
  for (int m = 32; m >= 1; m >>= 1) {
    s += __shfl_xor(s, m);
    s2 += __shfl_xor(s2, m);
  }
  __shared__ float red[8];
  int wid = threadIdx.x >> 6;
  if ((threadIdx.x & 63) == 0) { red[wid] = s; red[4 + wid] = s2; }
  __syncthreads();
  s = red[0] + red[1] + red[2] + red[3];
  s2 = red[4] + red[5] + red[6] + red[7];
  float mean = s * (1.f / (float)DD);
  float var = s2 * (1.f / (float)DD) - mean * mean;
  float rstd = rsqrtf(var + 1e-6f);
#pragma unroll
  for (int i = 0; i < 3; ++i) {
    int d = (threadIdx.x + 256 * i) * 2;
    float y0 = (v[i].x - mean) * rstd;
    float y1 = (v[i].y - mean) * rstd;
    if (modp) {
      float2 scv = *(const float2*)&modp[b * NMOD + sc + d];
      float2 shv = *(const float2*)&modp[b * NMOD + sh + d];
      y0 = y0 * (1.f + scv.x) + shv.x;
      y1 = y1 * (1.f + scv.y) + shv.y;
    }
    u32 w = (u32)f2bf(y0) | ((u32)f2bf(y1) << 16);
    *(u32*)&outp[d] = w;
  }
}

// ---- GEMM epilogue variants ----
// 0 bias->bf16 | 1 gelu->bf16 | 2 resid+g*(acc+bias)->f32 | 3 resid+acc+bias->f32
// 4 acc->bf16 partial at outp + zed*goff | 5 qkv scatter (q,k (b,h,t,d); v^T,
//   packed u32 t-pair stores where the 4 in-lane rows share a batch)
template <int EPI>
__device__ __forceinline__ void gemm_epi(
    const f32x4 (&acc)[4][4], int m0, int n0, int wm, int wn, int g, int r,
    int M, int N, const float* bias, void* outp, const float* resid,
    const float* modp, int goff, int rpb, int zed,
    u16* qb, u16* kb, u16* vtb) {
#pragma unroll
  for (int mi = 0; mi < 4; ++mi) {
#pragma unroll
    for (int ni = 0; ni < 4; ++ni) {
      const int col = n0 + wn + ni * 16 + r;
      float bv = 0.f;
      if constexpr (EPI != 4) bv = bias[col];
      if constexpr (EPI == 5) {
        const int row0 = m0 + wm + mi * 16 + g * 4;
        if (col >= 2 * DD) {
          // V^T: 4 in-lane rows = 4 consecutive t. Packed when same batch & in-range.
          const int cc = col - 2 * DD;
          const int h = cc >> 6, d = cc & 63;
          const int b0 = row0 / rpb;
          if (row0 + 3 < M && (row0 + 3) / rpb == b0) {
            const int t = goff + (row0 - b0 * rpb);
            u16* dst = &vtb[((size_t)b0 * HH + h) * (64 * NTP) + (size_t)d * NTP + t];
            u32 w0 = (u32)f2bf(acc[mi][ni][0] + bv) | ((u32)f2bf(acc[mi][ni][1] + bv) << 16);
            u32 w1 = (u32)f2bf(acc[mi][ni][2] + bv) | ((u32)f2bf(acc[mi][ni][3] + bv) << 16);
            *(u32*)&dst[0] = w0;
            *(u32*)&dst[2] = w1;
          } else {
#pragma unroll
            for (int j = 0; j < 4; ++j) {
              const int row = row0 + j;
              if (row >= M) continue;
              const int b = row / rpb;
              const int t = goff + (row - b * rpb);
              vtb[((size_t)b * HH + h) * (64 * NTP) + (size_t)d * NTP + t] =
                  f2bf(acc[mi][ni][j] + bv);
            }
          }
        } else {
          const bool isQ = col < DD;
          const int cc = isQ ? col : col - DD;
          const int h = cc >> 6, d = cc & 63;
          u16* dstb = isQ ? qb : kb;
#pragma unroll
          for (int j = 0; j < 4; ++j) {
            const int row = row0 + j;
            if (row >= M) continue;
            const int b = row / rpb;
            const int t = goff + (row - b * rpb);
            dstb[(((size_t)b * HH + h) * NT + t) * 64 + d] = f2bf(acc[mi][ni][j] + bv);
          }
        }
      } else {
#pragma unroll
        for (int j = 0; j < 4; ++j) {
          const int row = m0 + wm + mi * 16 + g * 4 + j;
          if (row >= M) continue;
          const size_t off = (size_t)row * N + col;
          float v = acc[mi][ni][j] + bv;
          if constexpr (EPI == 0) {
            ((u16*)outp)[off] = f2bf(v);
          } else if constexpr (EPI == 1) {
            ((u16*)outp)[off] = f2bf(gelu_t(v));
          } else if constexpr (EPI == 2) {
            const int b = row / rpb;
            ((float*)outp)[off] = resid[off] + modp[b * NMOD + goff + col] * v;
          } else if constexpr (EPI == 3) {
            ((float*)outp)[off] = resid[off] + v;
          } else {
            ((u16*)outp)[(size_t)zed * (size_t)goff + off] = f2bf(acc[mi][ni][j]);
          }
        }
      }
    }
  }
}

// ---- merged dual-stream pipelined bf16 MFMA GEMM, 128x128x32 tile ----
// Role 1 (m-blocks [0,yHi)) uses arg-set 1 / EPI1; role 2 uses set 2 / EPI2.
// blockIdx.z split-K (kzOff element offset) applies to BOTH roles.
// Panel-major rasterization (8-wide n-panels, m-fast) keeps each XCD chunk's
// B working-set ~3 MB (L2-resident). 2 x 16KB LDS double-buffer (32 KB total).
// Requires kLen % 32 == 0.
template <int EPI1, int EPI2>
__global__ LBG void k_gemm2(
    const u16* __restrict__ A1, const u16* __restrict__ Bt1, const float* __restrict__ bias1,
    int M1, int rpb1, int goff1, int kLen1,
    const u16* __restrict__ A2, const u16* __restrict__ Bt2, const float* __restrict__ bias2,
    int M2, int rpb2, int goff2, int kLen2,
    int yHi, int N, int lda, int ldb, int kzOff,
    void* __restrict__ out1, void* __restrict__ out2,
    const float* __restrict__ resid1, const float* __restrict__ resid2,
    const float* __restrict__ modp,
    u16* __restrict__ qb, u16* __restrict__ kb, u16* __restrict__ vtb) {
  __shared__ __align__(16) u16 sm[2 * 8192];  // 2 bufs x (A 4K u16 | B 4K u16) = 32 KB
  const int tid = threadIdx.x;
  const int lane = tid & 63;
  const int g = lane >> 4, r = lane & 15;
  const int wid = tid >> 6;

  // bijective XCD-aware tile remap (m204) over the full (gx x gyTot) grid
  const int gx = gridDim.x;
  const int gyTot = gridDim.y;
  const int nwg = gx * gyTot;
  int wg = blockIdx.y * gx + blockIdx.x;
  {
    int q = nwg >> 3, rr = nwg & 7;
    int xcd = wg & 7, sl = wg >> 3;
    wg = (xcd < rr ? xcd * (q + 1) : rr * (q + 1) + (xcd - rr) * q) + sl;
  }
  // panel-major (8-wide n-panels, m-fast within panel), bijective for any gx
  int mIdx, nIdx;
  {
    const int np1 = (gx - 1) >> 3;       // number of full 8-wide panels
    const int lastw = gx - np1 * 8;      // width of last panel (1..8)
    const int full = gyTot * 8;
    if (wg < np1 * full) {
      int p = wg / full, off = wg % full;
      mIdx = off >> 3;
      nIdx = p * 8 + (off & 7);
    } else {
      int off = wg - np1 * full;
      mIdx = off / lastw;
      nIdx = np1 * 8 + off % lastw;
    }
  }
  const bool role2 = mIdx >= yHi;

  const u16* A = role2 ? A2 : A1;
  const u16* Bt = role2 ? Bt2 : Bt1;
  const int M = role2 ? M2 : M1;
  const int kLen = role2 ? kLen2 : kLen1;
  const int m0 = (role2 ? (mIdx - yHi) : mIdx) * 128, n0 = nIdx * 128;
  const int wm = (wid >> 1) * 64, wn = (wid & 1) * 64;
  A += (size_t)blockIdx.z * kzOff;
  Bt += (size_t)blockIdx.z * kzOff;

  f32x4 acc[4][4];
#pragma unroll
  for (int i = 0; i < 4; ++i)
#pragma unroll
    for (int j = 0; j < 4; ++j) acc[i][j] = fzero4();

  // staging geometry (proven, 0 bank conflicts): wave wid owns chunks c0,c1;
  // lane l -> row c*16 + l/4, phys slot l&3 holds logical slot (l&3)^((l>>3)&3)
  const int rl = lane >> 2;
  const int slg = (lane & 3) ^ ((lane >> 3) & 3);
  const int c0 = wid * 2, c1 = wid * 2 + 1;
  const size_t aR0 = (size_t)imin(m0 + c0 * 16 + rl, M - 1) * lda + slg * 8;
  const size_t aR1 = (size_t)imin(m0 + c1 * 16 + rl, M - 1) * lda + slg * 8;
  const size_t bR0 = (size_t)(n0 + c0 * 16 + rl) * ldb + slg * 8;
  const size_t bR1 = (size_t)(n0 + c1 * 16 + rl) * ldb + slg * 8;

  int aOff[4], bOff[4];
#pragma unroll
  for (int mi = 0; mi < 4; ++mi) aOff[mi] = (wm + mi * 16 + r) * 32 + ((g ^ ((r >> 1) & 3)) * 8);
#pragma unroll
  for (int ni = 0; ni < 4; ++ni) bOff[ni] = 4096 + (wn + ni * 16 + r) * 32 + ((g ^ ((r >> 1) & 3)) * 8);

  const int nt = kLen >> 5;  // K-steps of 32

#define STAGE32(BI, T)                                      \
  do {                                                      \
    u16* bb = &sm[(BI) * 8192];                             \
    size_t kk = (size_t)(T) * 32;                           \
    glds16(A + aR0 + kk, bb + c0 * 512);                    \
    glds16(A + aR1 + kk, bb + c1 * 512);                    \
    glds16(Bt + bR0 + kk, bb + 4096 + c0 * 512);            \
    glds16(Bt + bR1 + kk, bb + 4096 + c1 * 512);            \
  } while (0)

  STAGE32(0, 0);

  for (int t = 0; t < nt; ++t) {
    WAITV0;                              // my 4 tile-t loads landed
    __builtin_amdgcn_s_barrier();        // tile-t published; tile-(t-1) reads retired
    SCHEDB;
    if (t + 1 < nt) STAGE32((t + 1) & 1, t + 1);  // lands during this tile's compute
    const u16* bb = &sm[(t & 1) * 8192];
    bf16x8 af[4], bfr[4];
#pragma unroll
    for (int mi = 0; mi < 4; ++mi) af[mi] = *(const bf16x8*)(bb + aOff[mi]);
#pragma unroll
    for (int ni = 0; ni < 4; ++ni) bfr[ni] = *(const bf16x8*)(bb + bOff[ni]);
    __builtin_amdgcn_s_setprio(1);
#pragma unroll
    for (int mi = 0; mi < 4; ++mi)
#pragma unroll
      for (int ni = 0; ni < 4; ++ni)
        acc[mi][ni] = __builtin_amdgcn_mfma_f32_16x16x32_bf16(af[mi], bfr[ni], acc[mi][ni], 0, 0, 0);
    __builtin_amdgcn_s_setprio(0);
    SCHEDB;  // keep this tile's body ahead of next iteration's WAITV0
  }
#undef STAGE32

  if (role2)
    gemm_epi<EPI2>(acc, m0, n0, wm, wn, g, r, M, N, bias2, out2, resid2, modp,
                   goff2, rpb2, blockIdx.z, qb, kb, vtb);
  else
    gemm_epi<EPI1>(acc, m0, n0, wm, wn, g, r, M, N, bias1, out1, resid1, modp,
                   goff1, rpb1, blockIdx.z, qb, kb, vtb);
}

// ---- split-K reduce for mlp2 (x rows then c rows), float2/u32-vectorized ----
__global__ void k_red2(const u16* __restrict__ p0x, const u16* __restrict__ p1x,
                       const float* __restrict__ residx, const float* __restrict__ bx,
                       const u16* __restrict__ p0c, const u16* __restrict__ p1c,
                       const float* __restrict__ residc, const float* __restrict__ bc,
                       float* __restrict__ outx, float* __restrict__ outc) {
  int row = blockIdx.x;
  const u16 *p0, *p1;
  const float *resid, *bias;
  float* out;
  size_t base;
  if (row < BB * NX) {
    p0 = p0x; p1 = p1x; resid = residx; bias = bx; out = outx;
    base = (size_t)row * DD;
  } else {
    int r2 = row - BB * NX;
    p0 = p0c; p1 = p1c; resid = residc; bias = bc; out = outc;
    base = (size_t)r2 * DD;
  }
#pragma unroll
  for (int i = 0; i < 3; ++i) {
    int j2 = (threadIdx.x + 256 * i) * 2;
    u32 a = *(const u32*)&p0[base + j2];
    u32 b = *(const u32*)&p1[base + j2];
    float2 rv = *(const float2*)&resid[base + j2];
    float2 bv = *(const float2*)&bias[j2];
    float2 o;
    o.x = rv.x + bv.x + bf2f((u16)a) + bf2f((u16)b);
    o.y = rv.y + bv.y + bf2f((u16)(a >> 16)) + bf2f((u16)(b >> 16));
    *(float2*)&out[base + j2] = o;
  }
}

// ---- flash attention: QBLK=128 (8 waves x 16 rows), KBLK=64, HD=64 ----
// Swapped QK^T (S^T = mfma(K,Q)): lane owns q-row (lane&15), 16 in-lane t.
// In-register softmax, packed b64 P-writes, next-tile K/V register prefetch
// (edge-specialized: clean path for 18/19 tiles), defer-max (THR=0, exact).
__global__ __launch_bounds__(512, 2) void k_attn(
    const u16* __restrict__ q, const u16* __restrict__ kk,
    const u16* __restrict__ vt, u16* __restrict__ ox, u16* __restrict__ oc) {
  __shared__ __align__(16) u16 Ks[64][72];
  __shared__ __align__(16) u16 Vs[64][72];
  __shared__ __align__(16) u16 Ps[8][16][72];

  const int lane = threadIdx.x & 63, wid = threadIdx.x >> 6;  // wid 0..7
  const int g = lane >> 4, r = lane & 15;
  const int q0 = blockIdx.x * 128;
  const int h = blockIdx.y, b = blockIdx.z;
  const size_t bh = (size_t)b * HH + h;
  const u16* qp = q + bh * (NT * 64);
  const u16* kp = kk + bh * (NT * 64);
  const u16* vp = vt + bh * (64 * NTP);

  const int qrow = imin(q0 + wid * 16 + r, NT - 1);
  u16x8 qr0 = *(const u16x8*)(qp + (size_t)qrow * 64 + g * 8);
  u16x8 qr1 = *(const u16x8*)(qp + (size_t)qrow * 64 + 32 + g * 8);
  bf16x8 qa0, qa1;
#pragma unroll
  for (int e = 0; e < 8; ++e) {
    qa0[e] = (short)f2bf(bf2f(qr0[e]) * 0.125f);
    qa1[e] = (short)f2bf(bf2f(qr1[e]) * 0.125f);
  }

  f32x4 oacc[4];
#pragma unroll
  for (int i = 0; i < 4; ++i) oacc[i] = fzero4();
  float mrow = -1e30f, lrow = 0.f;

  const int trA = threadIdx.x >> 3;
  const int ccA = (threadIdx.x & 7) * 8;

  u16x8 kreg, vreg;
#define LOADKV_C(T0)                                                   \
  do {                                                                 \
    kreg = *(const u16x8*)(kp + (size_t)((T0) + trA) * 64 + ccA);      \
    vreg = *(const u16x8*)(vp + (size_t)trA * NTP + (T0) + ccA);       \
  } while (0)
#define LOADKV_E(T0)                                                   \
  do {                                                                 \
    int tsrc = imin((T0) + trA, NT - 1);                               \
    kreg = *(const u16x8*)(kp + (size_t)tsrc * 64 + ccA);              \
    int tcol = (T0) + ccA;                                             \
    if (tcol + 8 <= NT) {                                              \
      vreg = *(const u16x8*)(vp + (size_t)trA * NTP + tcol);           \
    } else {                                                           \
      _Pragma("unroll")                                                \
      for (int e = 0; e < 8; ++e)                                      \
        vreg[e] = vp[(size_t)trA * NTP + imin(tcol + e, NT - 1)];      \
    }                                                                  \
  } while (0)

  LOADKV_C(0);

  for (int t0 = 0; t0 < NT; t0 += 64) {
    if (t0) __syncthreads();
    *(u16x8*)&Ks[trA][ccA] = kreg;
    *(u16x8*)&Vs[trA][ccA] = vreg;
    __syncthreads();
    if (t0 + 64 < NT) {
      if (t0 + 128 > NT) LOADKV_E(t0 + 64);  // next tile is the ragged last one
      else LOADKV_C(t0 + 64);
    }

    f32x4 s[4];
#pragma unroll
    for (int ni = 0; ni < 4; ++ni) {
      s[ni] = fzero4();
      s[ni] = __builtin_amdgcn_mfma_f32_16x16x32_bf16(*(const bf16x8*)&Ks[ni * 16 + r][g * 8], qa0, s[ni], 0, 0, 0);
      s[ni] = __builtin_amdgcn_mfma_f32_16x16x32_bf16(*(const bf16x8*)&Ks[ni * 16 + r][32 + g * 8], qa1, s[ni], 0, 0, 0);
    }

    float pv[4][4];
    float pm = -1e30f;
#pragma unroll
    for (int ni = 0; ni < 4; ++ni)
#pragma unroll
      for (int j = 0; j < 4; ++j) {
        int t = t0 + ni * 16 + g * 4 + j;
        float sv = (t < NT) ? s[ni][j] : -1e30f;
        pv[ni][j] = sv;
        pm = fmaxf(pm, sv);
      }
    pm = fmaxf(pm, __shfl_xor(pm, 16));
    pm = fmaxf(pm, __shfl_xor(pm, 32));

    // defer-max with THR=0: when no q-row's max grew, alpha == 1 exactly.
    const bool grow = !__all(pm <= mrow);
    float mn = mrow;
    if (grow) mn = fmaxf(mrow, pm);
    float rs = 0.f;
#pragma unroll
    for (int ni = 0; ni < 4; ++ni)
#pragma unroll
      for (int j = 0; j < 4; ++j) {
        float p = __expf(pv[ni][j] - mn);
        pv[ni][j] = p;
        rs += p;
      }
    rs += __shfl_xor(rs, 16);
    rs += __shfl_xor(rs, 32);
    if (grow) {
      float alpha = __expf(mrow - mn);
      mrow = mn;
      lrow = lrow * alpha + rs;
#pragma unroll
      for (int j = 0; j < 4; ++j) {
        float aj = __shfl(alpha, g * 4 + j);
#pragma unroll
        for (int ni = 0; ni < 4; ++ni) oacc[ni][j] *= aj;
      }
    } else {
      lrow += rs;
    }

#pragma unroll
    for (int ni = 0; ni < 4; ++ni) {
      u32x2 w;
      w[0] = (u32)f2bf(pv[ni][0]) | ((u32)f2bf(pv[ni][1]) << 16);
      w[1] = (u32)f2bf(pv[ni][2]) | ((u32)f2bf(pv[ni][3]) << 16);
      *(u32x2*)&Ps[wid][r][ni * 16 + g * 4] = w;
    }

    bf16x8 pa0 = *(const bf16x8*)&Ps[wid][r][g * 8];
    bf16x8 pa1 = *(const bf16x8*)&Ps[wid][r][32 + g * 8];
#pragma unroll
    for (int ni = 0; ni < 4; ++ni) {
      oacc[ni] = __builtin_amdgcn_mfma_f32_16x16x32_bf16(pa0, *(const bf16x8*)&Vs[ni * 16 + r][g * 8], oacc[ni], 0, 0, 0);
      oacc[ni] = __builtin_amdgcn_mfma_f32_16x16x32_bf16(pa1, *(const bf16x8*)&Vs[ni * 16 + r][32 + g * 8], oacc[ni], 0, 0, 0);
    }
  }
#undef LOADKV_C
#undef LOADKV_E

  float linv[4];
#pragma unroll
  for (int j = 0; j < 4; ++j) linv[j] = 1.f / __shfl(lrow, g * 4 + j);

#pragma unroll
  for (int ni = 0; ni < 4; ++ni)
#pragma unroll
    for (int j = 0; j < 4; ++j) {
      int tq = q0 + wid * 16 + g * 4 + j;
      if (tq >= NT) continue;
      float val = oacc[ni][j] * linv[j];
      int col = h * 64 + ni * 16 + r;
      if (tq < NX)
        ox[(size_t)(b * NX + tq) * DD + col] = f2bf(val);
      else
        oc[(size_t)(b * NC + tq - NX) * DD + col] = f2bf(val);
    }
}

extern "C" void kernel_launch(void* const* d_in, const int* in_sizes, int n_in,
                              void* d_out, int out_size, void* d_ws, size_t ws_size,
                              hipStream_t stream) {
  const float* x = (const float*)d_in[0];
  const float* c = (const float*)d_in[1];
  const float* vec = (const float*)d_in[2];
  const float* w_mod = (const float*)d_in[3];
  const float* b_mod = (const float*)d_in[4];
  const float* w_qkv_x = (const float*)d_in[5];
  const float* b_qkv_x = (const float*)d_in[6];
  const float* w_qkv_c = (const float*)d_in[7];
  const float* b_qkv_c = (const float*)d_in[8];
  const float* w_proj_x = (const float*)d_in[9];
  const float* b_proj_x = (const float*)d_in[10];
  const float* w_proj_c = (const float*)d_in[11];
  const float* b_proj_c = (const float*)d_in[12];
  const float* w1_x = (const float*)d_in[13];
  const float* b1_x = (const float*)d_in[14];
  const float* w2_x = (const float*)d_in[15];
  const float* b2_x = (const float*)d_in[16];
  const float* w1_c = (const float*)d_in[17];
  const float* b1_c = (const float*)d_in[18];
  const float* w2_c = (const float*)d_in[19];
  const float* b2_c = (const float*)d_in[20];

  if (ws_size < 229195776ull) return;  // workspace layout below needs this much

  char* ws = (char*)d_ws;
  // persistent: bf16-transposed weights + mod
  u16* wt_qkv_x = (u16*)(ws + 0);
  u16* wt_qkv_c = (u16*)(ws + 14155776);
  u16* wt_proj_x = (u16*)(ws + 28311552);
  u16* wt_proj_c = (u16*)(ws + 33030144);
  u16* wt_w1_x = (u16*)(ws + 37748736);
  u16* wt_w1_c = (u16*)(ws + 56623104);
  u16* wt_w2_x = (u16*)(ws + 75497472);
  u16* wt_w2_c = (u16*)(ws + 94371840);
  float* modf = (float*)(ws + 113246208);
  char* S = ws + 113393664;
  // slot 1 (14,475,264 B): x_n/c_n -> o_x/o_c -> xln/cln -> pb0 + pc0
  u16* xn = (u16*)(S);
  u16* cn = (u16*)(S + 12582912);
  // slot 2 (43,425,792 B): x2/c2 (f32); pb1 follows, then pc1 gap
  float* x2 = (float*)(S + 14475264);   // 25,165,824 B, ends S+39,641,088
  float* c2 = (float*)(S + 39641088);   //  3,784,704 B, ends S+43,425,792
  u16* pb0 = (u16*)(S);                 // 12,582,912 B (xn dead after mlp1 reads)
  u16* pc0 = (u16*)(S + 12582912);      //  1,892,352 B (cn dead after mlp1 reads)
  u16* pb1 = (u16*)(S + 43425792);      // 12,582,912 B (dead region after c2)
  u16* pc1 = (u16*)(S + 56008704);      //  1,892,352 B (gap before slot 3)
  const int PSTRIDE = 43425792 / 2;     // u16 stride pb0->pb1 AND pc0->pc1
  // slot 3 (57,901,056 B): q/k/vt -> h_x/h_c ; head also used as k_mod partials
  u16* qb = (u16*)(S + 57901056);
  u16* kb = (u16*)(S + 72376320);
  u16* vtb = (u16*)(S + 86851584);
  u16* hx = (u16*)(S + 57901056);
  u16* hc = (u16*)(S + 108232704);
  float* modpart = (float*)(S + 57901056);  // dead before q/k/vt written

  // 1) all 8 weight transposes (64x64 tiles) + mod partials in ONE dispatch
  {
    TDesc d;
    const float* Ws[8] = {w_qkv_x, w_qkv_c, w_proj_x, w_proj_c, w1_x, w1_c, w2_x, w2_c};
    u16* Wts[8] = {wt_qkv_x, wt_qkv_c, wt_proj_x, wt_proj_c, wt_w1_x, wt_w1_c, wt_w2_x, wt_w2_c};
    int Ks[8] = {DD, DD, DD, DD, DD, DD, MHD, MHD};
    int Ns[8] = {NQKV, NQKV, DD, DD, MHD, MHD, DD, DD};
    int off = 0;
    for (int i = 0; i < 8; ++i) {
      d.W[i] = Ws[i]; d.Wt[i] = Wts[i]; d.K[i] = Ks[i]; d.N[i] = Ns[i];
      d.off[i] = off;
      off += (Ns[i] >> 6) * (Ks[i] >> 6);
    }
    d.off[8] = off;
    d.vec = vec;
    d.w_mod = w_mod;
    d.part = modpart;
    k_transpose8<<<dim3(off + (NMOD / 256) * KSPL), 256, 0, stream>>>(d);
  }

  // 2) mod reduce (deterministic)
  k_mod_red<<<dim3(NMOD / 256), 256, 0, stream>>>(modpart, b_mod, modf);

  // 3) modulated LN (x+c merged) -> bf16
  k_ln2<<<dim3(BB * (NX + NC)), 256, 0, stream>>>(x, xn, c, cn, modf, 0, DD, 3 * DD, 4 * DD);

  // 4) merged QKV GEMM (x+c) with scatter epilogue -> qb,kb,vtb directly
  k_gemm2<5, 5><<<dim3(NQKV / 128, 37), 256, 0, stream>>>(
      xn, wt_qkv_x, b_qkv_x, BB * NX, NX, 0, DD,
      cn, wt_qkv_c, b_qkv_c, BB * NC, NC, NX, DD,
      32, NQKV, DD, DD, 0, nullptr, nullptr, nullptr, nullptr, nullptr,
      qb, kb, vtb);

  // 5) flash attention (QBLK=128, 8 waves) -> o (written into slot 1)
  k_attn<<<dim3((NT + 127) / 128, HH, BB), 512, 0, stream>>>(qb, kb, vtb, xn, cn);

  // 6) merged output projections with gated residual -> x2/c2 f32
  k_gemm2<2, 2><<<dim3(DD / 128, 37), 256, 0, stream>>>(
      xn, wt_proj_x, b_proj_x, BB * NX, NX, 2 * DD, DD,
      cn, wt_proj_c, b_proj_c, BB * NC, NC, 5 * DD, DD,
      32, DD, DD, DD, 0, x2, c2, x, c, modf, nullptr, nullptr, nullptr);

  // 7) plain LN (x+c merged) -> bf16
  k_ln2<<<dim3(BB * (NX + NC)), 256, 0, stream>>>(x2, xn, c2, cn, nullptr, 0, 0, 0, 0);

  // 8) merged MLP-1 (gelu) -> hx/hc
  k_gemm2<1, 1><<<dim3(MHD / 128, 37), 256, 0, stream>>>(
      xn, wt_w1_x, b1_x, BB * NX, NX, 0, DD,
      cn, wt_w1_c, b1_c, BB * NC, NC, 0, DD,
      32, MHD, DD, DD, 0, hx, hc, nullptr, nullptr, nullptr, nullptr, nullptr, nullptr);

  float* outx = (float*)d_out;
  float* outc = outx + (size_t)BB * NX * DD;
  // 9) merged MLP-2: BOTH streams split-K over z (96 K-steps every block)
  k_gemm2<4, 4><<<dim3(DD / 128, 37, 2), 256, 0, stream>>>(
      hx, wt_w2_x, b2_x, BB * NX, NX, PSTRIDE, MHD / 2,
      hc, wt_w2_c, b2_c, BB * NC, NC, PSTRIDE, MHD / 2,
      32, DD, MHD, MHD, MHD / 2, pb0, pc0, nullptr, nullptr, nullptr,
      nullptr, nullptr, nullptr);
  k_red2<<<dim3(BB * (NX + NC)), 256, 0, stream>>>(
      pb0, pb1, x2, b2_x, pc0, pc1, c2, b2_c, outx, outc);
}